// Round 1
// baseline (222.737 us; speedup 1.0000x reference)
//
#include <hip/hip_runtime.h>
#include <hip/hip_bf16.h>
#include <stdint.h>

#define B_ 8
#define N_ 2048
#define D_ 256
#define BN (B_*N_)
#define ISEG 16
#define IROWS (N_/ISEG)

typedef __bf16 bf16;
typedef bf16 bf16x8 __attribute__((ext_vector_type(8)));
typedef bf16 bf16x4 __attribute__((ext_vector_type(4)));
typedef float f32x4 __attribute__((ext_vector_type(4)));

// ---- kernel 0: transpose weights to bf16 [d][k] ----
__global__ __launch_bounds__(256) void k_transpose_w(
    const float* __restrict__ w, const float* __restrict__ hw,
    bf16* __restrict__ wt, bf16* __restrict__ hwt) {
  int t = blockIdx.x * 256 + threadIdx.x;   // 65536 total
  int d = t >> 8, k = t & 255;
  wt[t]  = (bf16)w[k * D_ + d];
  hwt[t] = (bf16)hw[k * D_ + d];
}

// ---- kernel 1: per-row a1/a2 + exp tables ----
__global__ __launch_bounds__(256) void k_prep(
    const float* __restrict__ x, const float* __restrict__ a,
    float* __restrict__ a1, float* __restrict__ e1, float* __restrict__ f1,
    float* __restrict__ a2, float* __restrict__ e2, float* __restrict__ f2) {
  int row = blockIdx.x * 4 + (threadIdx.x >> 6);   // one wave per row
  int lane = threadIdx.x & 63;
  float4 xv = *(const float4*)(x + (size_t)row * D_ + lane * 4);
  float4 u  = *(const float4*)(a + lane * 4);
  float4 v  = *(const float4*)(a + D_ + lane * 4);
  float s1 = xv.x*u.x + xv.y*u.y + xv.z*u.z + xv.w*u.w;
  float s2 = xv.x*v.x + xv.y*v.y + xv.z*v.z + xv.w*v.w;
  #pragma unroll
  for (int off = 32; off; off >>= 1) {
    s1 += __shfl_down(s1, off);
    s2 += __shfl_down(s2, off);
  }
  if (lane == 0) {
    a1[row] = s1; e1[row] = __expf(s1); f1[row] = __expf(0.2f * s1);
    a2[row] = s2; e2[row] = __expf(s2); f2[row] = __expf(0.2f * s2);
  }
}

// ---- kernel 2: h^T = (x@W)^T in bf16, MFMA ----
__global__ __launch_bounds__(256) void k_gemm_h(
    const float* __restrict__ x, const bf16* __restrict__ wt,
    bf16* __restrict__ hT) {
  int blk = blockIdx.x;            // 256 blocks
  int b = blk >> 5;
  int j0 = (blk & 31) * 64;
  int w = threadIdx.x >> 6, l = threadIdx.x & 63;
  int jr = j0 + w * 16 + (l & 15);
  const float* xrow = x + ((size_t)(b * N_ + jr)) * D_;
  int koff = 8 * (l >> 4);
  f32x4 acc[16];
  #pragma unroll
  for (int i = 0; i < 16; ++i) acc[i] = f32x4{0.f, 0.f, 0.f, 0.f};
  for (int kb = 0; kb < D_; kb += 32) {
    float4 xa = *(const float4*)(xrow + kb + koff);
    float4 xb = *(const float4*)(xrow + kb + koff + 4);
    bf16x8 af = { (bf16)xa.x, (bf16)xa.y, (bf16)xa.z, (bf16)xa.w,
                  (bf16)xb.x, (bf16)xb.y, (bf16)xb.z, (bf16)xb.w };
    #pragma unroll
    for (int dt = 0; dt < 16; ++dt) {
      bf16x8 bfr = *(const bf16x8*)(wt + (dt * 16 + (l & 15)) * D_ + kb + koff);
      acc[dt] = __builtin_amdgcn_mfma_f32_16x16x32_bf16(af, bfr, acc[dt], 0, 0, 0);
    }
  }
  int jw = j0 + w * 16 + (l >> 4) * 4;
  #pragma unroll
  for (int dt = 0; dt < 16; ++dt) {
    int d = dt * 16 + (l & 15);
    bf16x4 o = { (bf16)acc[dt][0], (bf16)acc[dt][1], (bf16)acc[dt][2], (bf16)acc[dt][3] };
    *(bf16x4*)(hT + ((size_t)(b * D_ + d)) * N_ + jw) = o;   // hT[b][d][j]
  }
}

// ---- kernel 3: column partial sums (softmax denom factors) + adj->bitmask ----
__global__ __launch_bounds__(256) void k_colstats(
    const int* __restrict__ adj,
    const float* __restrict__ a1, const float* __restrict__ e1, const float* __restrict__ f1,
    const float* __restrict__ a2,
    float* __restrict__ partA, float* __restrict__ partB,
    unsigned long long* __restrict__ mask64) {
  int blk = blockIdx.x;              // 1024 blocks
  int b  = blk >> 7;
  int jc = (blk >> 4) & 7;
  int is = blk & 15;
  int t = threadIdx.x, w = t >> 6;
  int j = jc * 256 + t;
  __shared__ float a1s[IROWS], e1s[IROWS], f1s[IROWS];
  int ibase = is * IROWS;
  if (t < IROWS) {
    int gi = b * N_ + ibase + t;
    a1s[t] = a1[gi]; e1s[t] = e1[gi]; f1s[t] = f1[gi];
  }
  __syncthreads();
  float va2 = a2[b * N_ + j];
  float SA = 0.f, SB = 0.f;
  const int* arow = adj + ((size_t)b * N_ + ibase) * N_ + j;
  unsigned long long* mrow = mask64 + ((size_t)b * N_ + ibase) * (N_/64) + (jc * 4 + w);
  #pragma unroll 4
  for (int ii = 0; ii < IROWS; ++ii) {
    int av = arow[(size_t)ii * N_];
    bool pred = (av != 0);
    float tt = a1s[ii] + va2;
    SA += (pred & (tt >  0.f)) ? e1s[ii] : 0.f;
    SB += (pred & (tt <= 0.f)) ? f1s[ii] : 0.f;
    unsigned long long bits = __ballot(pred);
    if ((t & 63) == 0) mrow[(size_t)ii * (N_/64)] = bits;
  }
  partA[(b * ISEG + is) * N_ + j] = SA;
  partB[(b * ISEG + is) * N_ + j] = SB;
}

// ---- kernel 4: finish column stats -> E2/s, F2/s ----
__global__ __launch_bounds__(256) void k_colfin(
    const float* __restrict__ partA, const float* __restrict__ partB,
    const float* __restrict__ e2, const float* __restrict__ f2,
    float* __restrict__ e2rs, float* __restrict__ f2rs) {
  int g = blockIdx.x * 256 + threadIdx.x;   // 16384
  int b = g >> 11, j = g & (N_ - 1);
  float SA = 0.f, SB = 0.f;
  #pragma unroll
  for (int is = 0; is < ISEG; ++is) {
    SA += partA[(b * ISEG + is) * N_ + j];
    SB += partB[(b * ISEG + is) * N_ + j];
  }
  float s = e2[g] * SA + f2[g] * SB;
  float rs = s > 0.f ? 1.f / s : 0.f;
  e2rs[g] = e2[g] * rs;
  f2rs[g] = f2[g] * rs;
}

// ---- kernel 5: fused att build + att@h MFMA + elu -> hid (bf16) ----
__global__ __launch_bounds__(256) void k_attmm(
    const bf16* __restrict__ hT, const unsigned char* __restrict__ maskB,
    const float* __restrict__ a1, const float* __restrict__ e1, const float* __restrict__ f1,
    const float* __restrict__ a2, const float* __restrict__ e2rs, const float* __restrict__ f2rs,
    bf16* __restrict__ hid) {
  __shared__ char sh[D_ * 128];    // 32 KB: row d, 64 j bf16 (128 B), 16B chunks XOR-swizzled
  int blk = blockIdx.x;            // 256 blocks
  int b  = blk & 7;                // XCD swizzle: whole batch on one XCD (L2 keeps hT_b)
  int i0 = (blk >> 3) * 64;
  int t = threadIdx.x, w = t >> 6, l = t & 63;
  int koff = 8 * (l >> 4);
  float a1r[4], e1r[4], f1r[4];
  #pragma unroll
  for (int is = 0; is < 4; ++is) {
    int gi = b * N_ + i0 + is * 16 + (l & 15);
    a1r[is] = a1[gi]; e1r[is] = e1[gi]; f1r[is] = f1[gi];
  }
  const bf16* hTb = hT + (size_t)b * D_ * N_;
  const unsigned char* mbase = maskB + ((size_t)(b * N_ + i0)) * (N_ / 8);
  const float* a2b = a2 + b * N_;
  const float* eb = e2rs + b * N_;
  const float* fb = f2rs + b * N_;
  f32x4 acc[4][4];
  #pragma unroll
  for (int is = 0; is < 4; ++is)
    #pragma unroll
    for (int ds = 0; ds < 4; ++ds) acc[is][ds] = f32x4{0.f, 0.f, 0.f, 0.f};

  for (int kb = 0; kb < N_; kb += 64) {
    // build att A-fragments in registers (global reads only -> overlaps barrier)
    bf16x8 afrag[2][4];
    #pragma unroll
    for (int kh = 0; kh < 2; ++kh) {
      int jb = kb + kh * 32 + koff;
      float4 p0 = *(const float4*)(a2b + jb);
      float4 p1 = *(const float4*)(a2b + jb + 4);
      float4 q0 = *(const float4*)(eb + jb);
      float4 q1 = *(const float4*)(eb + jb + 4);
      float4 r0 = *(const float4*)(fb + jb);
      float4 r1 = *(const float4*)(fb + jb + 4);
      float a2v[8] = {p0.x,p0.y,p0.z,p0.w,p1.x,p1.y,p1.z,p1.w};
      float ev[8]  = {q0.x,q0.y,q0.z,q0.w,q1.x,q1.y,q1.z,q1.w};
      float fv[8]  = {r0.x,r0.y,r0.z,r0.w,r1.x,r1.y,r1.z,r1.w};
      #pragma unroll
      for (int is = 0; is < 4; ++is) {
        unsigned int mb = mbase[(is * 16 + (l & 15)) * (N_ / 8) + (jb >> 3)];
        bf16x8 af;
        #pragma unroll
        for (int e = 0; e < 8; ++e) {
          float tt = a1r[is] + a2v[e];
          float vv = tt > 0.f ? e1r[is] * ev[e] : f1r[is] * fv[e];
          vv = ((mb >> e) & 1u) ? vv : 0.f;
          af[e] = (bf16)vv;
        }
        afrag[kh][is] = af;
      }
    }
    __syncthreads();   // previous iteration's LDS reads complete
    // stage hT tile [256 d][64 j] with per-row XOR swizzle of 16B chunks
    #pragma unroll
    for (int s = 0; s < 8; ++s) {
      int chunk = t + s * 256;           // 0..2047
      int d = chunk >> 3, cq = chunk & 7;
      uint4 vv = *(const uint4*)(hTb + (size_t)d * N_ + kb + cq * 8);
      *(uint4*)(sh + d * 128 + ((cq ^ (d & 7)) * 16)) = vv;
    }
    __syncthreads();
    #pragma unroll
    for (int kh = 0; kh < 2; ++kh) {
      bf16x8 bfrag[4];
      #pragma unroll
      for (int ds = 0; ds < 4; ++ds) {
        int d = w * 64 + ds * 16 + (l & 15);
        int kq = kh * 4 + (l >> 4);
        bfrag[ds] = *(const bf16x8*)(sh + d * 128 + ((kq ^ (d & 7)) * 16));
      }
      #pragma unroll
      for (int is = 0; is < 4; ++is)
        #pragma unroll
        for (int ds = 0; ds < 4; ++ds)
          acc[is][ds] = __builtin_amdgcn_mfma_f32_16x16x32_bf16(
              afrag[kh][is], bfrag[ds], acc[is][ds], 0, 0, 0);
    }
  }
  // epilogue: elu -> hid bf16 [b][i][d]
  #pragma unroll
  for (int is = 0; is < 4; ++is) {
    int ib = i0 + is * 16 + (l >> 4) * 4;
    #pragma unroll
    for (int ds = 0; ds < 4; ++ds) {
      int d = w * 64 + ds * 16 + (l & 15);
      #pragma unroll
      for (int r = 0; r < 4; ++r) {
        float vv = acc[is][ds][r];
        float hv = vv > 0.f ? vv : __expf(vv) - 1.f;
        hid[((size_t)(b * N_ + ib + r)) * D_ + d] = (bf16)hv;
      }
    }
  }
}

// ---- kernel 6: out = hid @ han_w + han_b (f32 out) ----
__global__ __launch_bounds__(256) void k_gemm_out(
    const bf16* __restrict__ hid, const bf16* __restrict__ hwt,
    const float* __restrict__ hb, float* __restrict__ out) {
  int blk = blockIdx.x;            // 256 blocks
  int b = blk >> 5;
  int i0 = (blk & 31) * 64;
  int w = threadIdx.x >> 6, l = threadIdx.x & 63;
  int ir = i0 + w * 16 + (l & 15);
  const bf16* hrow = hid + ((size_t)(b * N_ + ir)) * D_;
  int koff = 8 * (l >> 4);
  f32x4 acc[16];
  #pragma unroll
  for (int i = 0; i < 16; ++i) acc[i] = f32x4{0.f, 0.f, 0.f, 0.f};
  for (int kb = 0; kb < D_; kb += 32) {
    bf16x8 af = *(const bf16x8*)(hrow + kb + koff);
    #pragma unroll
    for (int dt = 0; dt < 16; ++dt) {
      bf16x8 bfr = *(const bf16x8*)(hwt + (dt * 16 + (l & 15)) * D_ + kb + koff);
      acc[dt] = __builtin_amdgcn_mfma_f32_16x16x32_bf16(af, bfr, acc[dt], 0, 0, 0);
    }
  }
  int iw = i0 + w * 16 + (l >> 4) * 4;
  #pragma unroll
  for (int dt = 0; dt < 16; ++dt) {
    int d = dt * 16 + (l & 15);
    float bias = hb[d];
    #pragma unroll
    for (int r = 0; r < 4; ++r)
      out[((size_t)(b * N_ + iw + r)) * D_ + d] = acc[dt][r] + bias;
  }
}

extern "C" void kernel_launch(void* const* d_in, const int* in_sizes, int n_in,
                              void* d_out, int out_size, void* d_ws, size_t ws_size,
                              hipStream_t stream) {
  (void)in_sizes; (void)n_in; (void)out_size; (void)ws_size;
  const float* x   = (const float*)d_in[0];
  const int*   adj = (const int*)d_in[1];
  const float* W   = (const float*)d_in[2];
  const float* a   = (const float*)d_in[3];
  const float* hw  = (const float*)d_in[4];
  const float* hb  = (const float*)d_in[5];
  float* out = (float*)d_out;

  char* ws = (char*)d_ws;
  size_t off = 0;
  auto alloc = [&](size_t bytes) -> char* {
    char* p = ws + off;
    off += (bytes + 255) & ~(size_t)255;
    return p;
  };
  float* a1   = (float*)alloc(BN * 4);
  float* e1   = (float*)alloc(BN * 4);
  float* f1   = (float*)alloc(BN * 4);
  float* a2   = (float*)alloc(BN * 4);
  float* e2   = (float*)alloc(BN * 4);
  float* f2   = (float*)alloc(BN * 4);
  float* e2rs = (float*)alloc(BN * 4);
  float* f2rs = (float*)alloc(BN * 4);
  float* partA = (float*)alloc((size_t)B_ * ISEG * N_ * 4);
  float* partB = (float*)alloc((size_t)B_ * ISEG * N_ * 4);
  unsigned long long* mask64 = (unsigned long long*)alloc((size_t)BN * (N_ / 8)); // 4 MB
  bf16* hT  = (bf16*)alloc((size_t)B_ * D_ * N_ * 2);   // 8 MB
  bf16* hid = (bf16*)alloc((size_t)BN * D_ * 2);        // 8 MB
  bf16* wt  = (bf16*)alloc((size_t)D_ * D_ * 2);
  bf16* hwt = (bf16*)alloc((size_t)D_ * D_ * 2);

  k_transpose_w<<<256, 256, 0, stream>>>(W, hw, wt, hwt);
  k_prep<<<BN / 4, 256, 0, stream>>>(x, a, a1, e1, f1, a2, e2, f2);
  k_gemm_h<<<256, 256, 0, stream>>>(x, wt, hT);
  k_colstats<<<B_ * 8 * ISEG, 256, 0, stream>>>(adj, a1, e1, f1, a2, partA, partB, mask64);
  k_colfin<<<BN / 256, 256, 0, stream>>>(partA, partB, e2, f2, e2rs, f2rs);
  k_attmm<<<256, 256, 0, stream>>>(hT, (const unsigned char*)mask64,
                                   a1, e1, f1, a2, e2rs, f2rs, hid);
  k_gemm_out<<<256, 256, 0, stream>>>(hid, hwt, hb, out);
}

// Round 2
// 183.411 us; speedup vs baseline: 1.2144x; 1.2144x over previous
//
#include <hip/hip_runtime.h>
#include <hip/hip_bf16.h>
#include <stdint.h>

#define B_ 8
#define N_ 2048
#define D_ 256
#define BN (B_*N_)
#define ISEG 16
#define IROWS (N_/ISEG)

typedef __bf16 bf16;
typedef bf16 bf16x8 __attribute__((ext_vector_type(8)));
typedef bf16 bf16x4 __attribute__((ext_vector_type(4)));
typedef float f32x4 __attribute__((ext_vector_type(4)));

// ---- kernel 0: transpose weights to bf16 [d][k] ----
__global__ __launch_bounds__(256) void k_transpose_w(
    const float* __restrict__ w, const float* __restrict__ hw,
    bf16* __restrict__ wt, bf16* __restrict__ hwt) {
  int t = blockIdx.x * 256 + threadIdx.x;   // 65536 total
  int d = t >> 8, k = t & 255;
  wt[t]  = (bf16)w[k * D_ + d];
  hwt[t] = (bf16)hw[k * D_ + d];
}

// ---- kernel 1: h^T = (x@W)^T in bf16 (MFMA), fused with a1/a2 row stats ----
__global__ __launch_bounds__(256) void k_gemm_h(
    const float* __restrict__ x, const bf16* __restrict__ wt,
    const float* __restrict__ avec, bf16* __restrict__ hT,
    float* __restrict__ a1, float* __restrict__ e1, float* __restrict__ f1,
    float* __restrict__ a2, float* __restrict__ e2, float* __restrict__ f2) {
  int blk = blockIdx.x;            // 256 blocks
  int b = blk >> 5;
  int j0 = (blk & 31) * 64;
  int w = threadIdx.x >> 6, l = threadIdx.x & 63;
  int jr = j0 + w * 16 + (l & 15);
  const float* xrow = x + ((size_t)(b * N_ + jr)) * D_;
  int koff = 8 * (l >> 4);
  f32x4 acc[16];
  #pragma unroll
  for (int i = 0; i < 16; ++i) acc[i] = f32x4{0.f, 0.f, 0.f, 0.f};
  float s1 = 0.f, s2 = 0.f;
  for (int kb = 0; kb < D_; kb += 32) {
    float4 xa = *(const float4*)(xrow + kb + koff);
    float4 xb = *(const float4*)(xrow + kb + koff + 4);
    float4 ua = *(const float4*)(avec + kb + koff);
    float4 ub = *(const float4*)(avec + kb + koff + 4);
    float4 va = *(const float4*)(avec + D_ + kb + koff);
    float4 vb = *(const float4*)(avec + D_ + kb + koff + 4);
    s1 = fmaf(xa.x, ua.x, fmaf(xa.y, ua.y, fmaf(xa.z, ua.z, fmaf(xa.w, ua.w, s1))));
    s1 = fmaf(xb.x, ub.x, fmaf(xb.y, ub.y, fmaf(xb.z, ub.z, fmaf(xb.w, ub.w, s1))));
    s2 = fmaf(xa.x, va.x, fmaf(xa.y, va.y, fmaf(xa.z, va.z, fmaf(xa.w, va.w, s2))));
    s2 = fmaf(xb.x, vb.x, fmaf(xb.y, vb.y, fmaf(xb.z, vb.z, fmaf(xb.w, vb.w, s2))));
    bf16x8 af = { (bf16)xa.x, (bf16)xa.y, (bf16)xa.z, (bf16)xa.w,
                  (bf16)xb.x, (bf16)xb.y, (bf16)xb.z, (bf16)xb.w };
    #pragma unroll
    for (int dt = 0; dt < 16; ++dt) {
      bf16x8 bfr = *(const bf16x8*)(wt + (dt * 16 + (l & 15)) * D_ + kb + koff);
      acc[dt] = __builtin_amdgcn_mfma_f32_16x16x32_bf16(af, bfr, acc[dt], 0, 0, 0);
    }
  }
  // row-stat reduction: lanes l, l^16, l^32, l^48 share row jr
  s1 += __shfl_xor(s1, 16); s1 += __shfl_xor(s1, 32);
  s2 += __shfl_xor(s2, 16); s2 += __shfl_xor(s2, 32);
  if (l < 16) {
    int row = b * N_ + j0 + w * 16 + l;
    a1[row] = s1; e1[row] = __expf(s1); f1[row] = __expf(0.2f * s1);
    a2[row] = s2; e2[row] = __expf(s2); f2[row] = __expf(0.2f * s2);
  }
  int jw = j0 + w * 16 + (l >> 4) * 4;
  #pragma unroll
  for (int dt = 0; dt < 16; ++dt) {
    int d = dt * 16 + (l & 15);
    bf16x4 o = { (bf16)acc[dt][0], (bf16)acc[dt][1], (bf16)acc[dt][2], (bf16)acc[dt][3] };
    *(bf16x4*)(hT + ((size_t)(b * D_ + d)) * N_ + jw) = o;   // hT[b][d][j]
  }
}

// ---- kernel 2: column partial sums (softmax denom factors) + adj->bitmask ----
__global__ __launch_bounds__(256) void k_colstats(
    const int* __restrict__ adj,
    const float* __restrict__ a1, const float* __restrict__ e1, const float* __restrict__ f1,
    const float* __restrict__ a2,
    float* __restrict__ partA, float* __restrict__ partB,
    unsigned long long* __restrict__ mask64) {
  int blk = blockIdx.x;              // 1024 blocks
  int b  = blk >> 7;
  int jc = (blk >> 4) & 7;
  int is = blk & 15;
  int t = threadIdx.x, w = t >> 6;
  int j = jc * 256 + t;
  __shared__ float a1s[IROWS], e1s[IROWS], f1s[IROWS];
  int ibase = is * IROWS;
  if (t < IROWS) {
    int gi = b * N_ + ibase + t;
    a1s[t] = a1[gi]; e1s[t] = e1[gi]; f1s[t] = f1[gi];
  }
  __syncthreads();
  float va2 = a2[b * N_ + j];
  float SA = 0.f, SB = 0.f;
  const int* arow = adj + ((size_t)b * N_ + ibase) * N_ + j;
  unsigned long long* mrow = mask64 + ((size_t)b * N_ + ibase) * (N_/64) + (jc * 4 + w);
  #pragma unroll 4
  for (int ii = 0; ii < IROWS; ++ii) {
    int av = arow[(size_t)ii * N_];
    bool pred = (av != 0);
    float tt = a1s[ii] + va2;
    SA += (pred & (tt >  0.f)) ? e1s[ii] : 0.f;
    SB += (pred & (tt <= 0.f)) ? f1s[ii] : 0.f;
    unsigned long long bits = __ballot(pred);
    if ((t & 63) == 0) mrow[(size_t)ii * (N_/64)] = bits;
  }
  partA[(b * ISEG + is) * N_ + j] = SA;
  partB[(b * ISEG + is) * N_ + j] = SB;
}

// ---- kernel 3: finish column stats -> E2/s, F2/s ----
__global__ __launch_bounds__(256) void k_colfin(
    const float* __restrict__ partA, const float* __restrict__ partB,
    const float* __restrict__ e2, const float* __restrict__ f2,
    float* __restrict__ e2rs, float* __restrict__ f2rs) {
  int g = blockIdx.x * 256 + threadIdx.x;   // 16384
  int b = g >> 11, j = g & (N_ - 1);
  float SA = 0.f, SB = 0.f;
  #pragma unroll
  for (int is = 0; is < ISEG; ++is) {
    SA += partA[(b * ISEG + is) * N_ + j];
    SB += partB[(b * ISEG + is) * N_ + j];
  }
  float s = e2[g] * SA + f2[g] * SB;
  float rs = s > 0.f ? 1.f / s : 0.f;
  e2rs[g] = e2[g] * rs;
  f2rs[g] = f2[g] * rs;
}

// ---- kernel 4: fused att build (cooperative, LDS) + att@h MFMA + elu ----
// grid 512: b = blk&7 (XCD pin, hT_b L2-resident), i-tile 32.
// att tile [32 i][64 j] bf16 built ONCE per block per K-step into dbuf LDS;
// B-fragments (hT) read directly from L2 (no LDS staging).
__global__ __launch_bounds__(256) void k_attmm(
    const bf16* __restrict__ hT, const unsigned char* __restrict__ maskB,
    const float* __restrict__ a1, const float* __restrict__ e1, const float* __restrict__ f1,
    const float* __restrict__ a2, const float* __restrict__ e2rs, const float* __restrict__ f2rs,
    bf16* __restrict__ hid) {
  __shared__ char satt[2][32 * 128];   // 8 KB: row i (128 B), 16B chunks XOR-swizzled
  int blk = blockIdx.x;                // 512 blocks
  int b  = blk & 7;
  int i0 = (blk >> 3) * 32;
  int t = threadIdx.x, w = t >> 6, l = t & 63;
  int l15 = l & 15, lg = l >> 4;
  // build role: row ib (4 rows/8-thread group... 8 threads per row), 8 cols each
  int ib = t >> 3, jq = t & 7;
  int gi = b * N_ + i0 + ib;
  float a1i = a1[gi], e1i = e1[gi], f1i = f1[gi];
  const unsigned char* mrow = maskB + (size_t)gi * (N_ / 8);
  const float* a2b = a2 + b * N_;
  const float* eb  = e2rs + b * N_;
  const float* fb  = f2rs + b * N_;
  const bf16* hTb = hT + (size_t)b * D_ * N_;
  f32x4 acc[2][4];
  #pragma unroll
  for (int is = 0; is < 2; ++is)
    #pragma unroll
    for (int ds = 0; ds < 4; ++ds) acc[is][ds] = f32x4{0.f, 0.f, 0.f, 0.f};

  #pragma unroll 2
  for (int kb = 0; kb < N_; kb += 64) {
    char* sb = satt[(kb >> 6) & 1];
    // ---- build 8 att entries (j = kb + jq*8 + e) ----
    int jbase = kb + jq * 8;
    float4 p0 = *(const float4*)(a2b + jbase);
    float4 p1 = *(const float4*)(a2b + jbase + 4);
    float4 q0 = *(const float4*)(eb + jbase);
    float4 q1 = *(const float4*)(eb + jbase + 4);
    float4 r0 = *(const float4*)(fb + jbase);
    float4 r1 = *(const float4*)(fb + jbase + 4);
    unsigned int mb = mrow[(kb >> 3) + jq];
    float a2v[8] = {p0.x,p0.y,p0.z,p0.w,p1.x,p1.y,p1.z,p1.w};
    float ev[8]  = {q0.x,q0.y,q0.z,q0.w,q1.x,q1.y,q1.z,q1.w};
    float fv[8]  = {r0.x,r0.y,r0.z,r0.w,r1.x,r1.y,r1.z,r1.w};
    bf16x8 av;
    #pragma unroll
    for (int e = 0; e < 8; ++e) {
      float tt = a1i + a2v[e];
      bool sel = tt > 0.f;
      float vv = (sel ? e1i : f1i) * (sel ? ev[e] : fv[e]);
      float vm = ((mb >> e) & 1u) ? vv : 0.f;
      av[e] = (bf16)vm;
    }
    // ---- B-fragments from L2 before the barrier (latency hides under it) ----
    bf16x8 bfr[2][4];
    #pragma unroll
    for (int kh = 0; kh < 2; ++kh)
      #pragma unroll
      for (int ds = 0; ds < 4; ++ds)
        bfr[kh][ds] = *(const bf16x8*)(
            hTb + (size_t)(w * 64 + ds * 16 + l15) * N_ + kb + kh * 32 + lg * 8);
    *(bf16x8*)(sb + ib * 128 + ((jq ^ (ib & 7)) * 16)) = av;
    __syncthreads();
    // ---- MFMA: A from LDS att tile, B in regs ----
    #pragma unroll
    for (int kh = 0; kh < 2; ++kh) {
      int kq = kh * 4 + lg;
      bf16x8 afr[2];
      #pragma unroll
      for (int is = 0; is < 2; ++is) {
        int ra = is * 16 + l15;
        afr[is] = *(const bf16x8*)(sb + ra * 128 + ((kq ^ (ra & 7)) * 16));
      }
      #pragma unroll
      for (int is = 0; is < 2; ++is)
        #pragma unroll
        for (int ds = 0; ds < 4; ++ds)
          acc[is][ds] = __builtin_amdgcn_mfma_f32_16x16x32_bf16(
              afr[is], bfr[kh][ds], acc[is][ds], 0, 0, 0);
    }
  }
  // ---- epilogue: elu -> hid bf16 [b][i][d] ----
  #pragma unroll
  for (int is = 0; is < 2; ++is) {
    int ibr = i0 + is * 16 + lg * 4;
    #pragma unroll
    for (int ds = 0; ds < 4; ++ds) {
      int d = w * 64 + ds * 16 + l15;
      #pragma unroll
      for (int r = 0; r < 4; ++r) {
        float vv = acc[is][ds][r];
        float hv = vv > 0.f ? vv : __expf(vv) - 1.f;
        hid[((size_t)(b * N_ + ibr + r)) * D_ + d] = (bf16)hv;
      }
    }
  }
}

// ---- kernel 5: out = hid @ han_w + han_b (f32 out) ----
__global__ __launch_bounds__(256) void k_gemm_out(
    const bf16* __restrict__ hid, const bf16* __restrict__ hwt,
    const float* __restrict__ hb, float* __restrict__ out) {
  int blk = blockIdx.x;            // 256 blocks
  int b = blk >> 5;
  int i0 = (blk & 31) * 64;
  int w = threadIdx.x >> 6, l = threadIdx.x & 63;
  int ir = i0 + w * 16 + (l & 15);
  const bf16* hrow = hid + ((size_t)(b * N_ + ir)) * D_;
  int koff = 8 * (l >> 4);
  f32x4 acc[16];
  #pragma unroll
  for (int i = 0; i < 16; ++i) acc[i] = f32x4{0.f, 0.f, 0.f, 0.f};
  for (int kb = 0; kb < D_; kb += 32) {
    bf16x8 af = *(const bf16x8*)(hrow + kb + koff);
    #pragma unroll
    for (int dt = 0; dt < 16; ++dt) {
      bf16x8 bfr = *(const bf16x8*)(hwt + (dt * 16 + (l & 15)) * D_ + kb + koff);
      acc[dt] = __builtin_amdgcn_mfma_f32_16x16x32_bf16(af, bfr, acc[dt], 0, 0, 0);
    }
  }
  int iw = i0 + w * 16 + (l >> 4) * 4;
  #pragma unroll
  for (int dt = 0; dt < 16; ++dt) {
    int d = dt * 16 + (l & 15);
    float bias = hb[d];
    #pragma unroll
    for (int r = 0; r < 4; ++r)
      out[((size_t)(b * N_ + iw + r)) * D_ + d] = acc[dt][r] + bias;
  }
}

extern "C" void kernel_launch(void* const* d_in, const int* in_sizes, int n_in,
                              void* d_out, int out_size, void* d_ws, size_t ws_size,
                              hipStream_t stream) {
  (void)in_sizes; (void)n_in; (void)out_size; (void)ws_size;
  const float* x   = (const float*)d_in[0];
  const int*   adj = (const int*)d_in[1];
  const float* W   = (const float*)d_in[2];
  const float* a   = (const float*)d_in[3];
  const float* hw  = (const float*)d_in[4];
  const float* hb  = (const float*)d_in[5];
  float* out = (float*)d_out;

  char* ws = (char*)d_ws;
  size_t off = 0;
  auto alloc = [&](size_t bytes) -> char* {
    char* p = ws + off;
    off += (bytes + 255) & ~(size_t)255;
    return p;
  };
  float* a1   = (float*)alloc(BN * 4);
  float* e1   = (float*)alloc(BN * 4);
  float* f1   = (float*)alloc(BN * 4);
  float* a2   = (float*)alloc(BN * 4);
  float* e2   = (float*)alloc(BN * 4);
  float* f2   = (float*)alloc(BN * 4);
  float* e2rs = (float*)alloc(BN * 4);
  float* f2rs = (float*)alloc(BN * 4);
  float* partA = (float*)alloc((size_t)B_ * ISEG * N_ * 4);
  float* partB = (float*)alloc((size_t)B_ * ISEG * N_ * 4);
  unsigned long long* mask64 = (unsigned long long*)alloc((size_t)BN * (N_ / 8)); // 4 MB
  bf16* hT  = (bf16*)alloc((size_t)B_ * D_ * N_ * 2);   // 8 MB
  bf16* hid = (bf16*)alloc((size_t)BN * D_ * 2);        // 8 MB
  bf16* wt  = (bf16*)alloc((size_t)D_ * D_ * 2);
  bf16* hwt = (bf16*)alloc((size_t)D_ * D_ * 2);

  k_transpose_w<<<256, 256, 0, stream>>>(W, hw, wt, hwt);
  k_gemm_h<<<256, 256, 0, stream>>>(x, wt, a, hT, a1, e1, f1, a2, e2, f2);
  k_colstats<<<B_ * 8 * ISEG, 256, 0, stream>>>(adj, a1, e1, f1, a2, partA, partB, mask64);
  k_colfin<<<BN / 256, 256, 0, stream>>>(partA, partB, e2, f2, e2rs, f2rs);
  k_attmm<<<512, 256, 0, stream>>>(hT, (const unsigned char*)mask64,
                                   a1, e1, f1, a2, e2rs, f2rs, hid);
  k_gemm_out<<<256, 256, 0, stream>>>(hid, hwt, hb, out);
}

// Round 3
// 156.485 us; speedup vs baseline: 1.4234x; 1.1721x over previous
//
#include <hip/hip_runtime.h>
#include <hip/hip_bf16.h>
#include <stdint.h>

#define B_ 8
#define N_ 2048
#define D_ 256
#define BN (B_*N_)
#define NSEG 64
#define SROWS (N_/NSEG)   // 32 rows per segment

typedef __bf16 bf16;
typedef bf16 bf16x8 __attribute__((ext_vector_type(8)));
typedef bf16 bf16x4 __attribute__((ext_vector_type(4)));
typedef float f32x4 __attribute__((ext_vector_type(4)));

// ---- kernel 0: transpose weights to bf16 [d][k] ----
__global__ __launch_bounds__(256) void k_transpose_w(
    const float* __restrict__ w, const float* __restrict__ hw,
    bf16* __restrict__ wt, bf16* __restrict__ hwt) {
  int t = blockIdx.x * 256 + threadIdx.x;   // 65536 total
  int d = t >> 8, k = t & 255;
  wt[t]  = (bf16)w[k * D_ + d];
  hwt[t] = (bf16)hw[k * D_ + d];
}

// ---- kernel 1: h^T = (x@W)^T in bf16 (MFMA), fused with a1/a2 row stats ----
__global__ __launch_bounds__(256) void k_gemm_h(
    const float* __restrict__ x, const bf16* __restrict__ wt,
    const float* __restrict__ avec, bf16* __restrict__ hT,
    float* __restrict__ a1, float* __restrict__ e1, float* __restrict__ f1,
    float* __restrict__ a2, float* __restrict__ e2, float* __restrict__ f2) {
  int blk = blockIdx.x;            // 256 blocks
  int b = blk >> 5;
  int j0 = (blk & 31) * 64;
  int w = threadIdx.x >> 6, l = threadIdx.x & 63;
  int jr = j0 + w * 16 + (l & 15);
  const float* xrow = x + ((size_t)(b * N_ + jr)) * D_;
  int koff = 8 * (l >> 4);
  f32x4 acc[16];
  #pragma unroll
  for (int i = 0; i < 16; ++i) acc[i] = f32x4{0.f, 0.f, 0.f, 0.f};
  float s1 = 0.f, s2 = 0.f;
  for (int kb = 0; kb < D_; kb += 32) {
    float4 xa = *(const float4*)(xrow + kb + koff);
    float4 xb = *(const float4*)(xrow + kb + koff + 4);
    float4 ua = *(const float4*)(avec + kb + koff);
    float4 ub = *(const float4*)(avec + kb + koff + 4);
    float4 va = *(const float4*)(avec + D_ + kb + koff);
    float4 vb = *(const float4*)(avec + D_ + kb + koff + 4);
    s1 = fmaf(xa.x, ua.x, fmaf(xa.y, ua.y, fmaf(xa.z, ua.z, fmaf(xa.w, ua.w, s1))));
    s1 = fmaf(xb.x, ub.x, fmaf(xb.y, ub.y, fmaf(xb.z, ub.z, fmaf(xb.w, ub.w, s1))));
    s2 = fmaf(xa.x, va.x, fmaf(xa.y, va.y, fmaf(xa.z, va.z, fmaf(xa.w, va.w, s2))));
    s2 = fmaf(xb.x, vb.x, fmaf(xb.y, vb.y, fmaf(xb.z, vb.z, fmaf(xb.w, vb.w, s2))));
    bf16x8 af = { (bf16)xa.x, (bf16)xa.y, (bf16)xa.z, (bf16)xa.w,
                  (bf16)xb.x, (bf16)xb.y, (bf16)xb.z, (bf16)xb.w };
    #pragma unroll
    for (int dt = 0; dt < 16; ++dt) {
      bf16x8 bfr = *(const bf16x8*)(wt + (dt * 16 + (l & 15)) * D_ + kb + koff);
      acc[dt] = __builtin_amdgcn_mfma_f32_16x16x32_bf16(af, bfr, acc[dt], 0, 0, 0);
    }
  }
  // row-stat reduction: lanes l, l^16, l^32, l^48 share row jr
  s1 += __shfl_xor(s1, 16); s1 += __shfl_xor(s1, 32);
  s2 += __shfl_xor(s2, 16); s2 += __shfl_xor(s2, 32);
  if (l < 16) {
    int row = b * N_ + j0 + w * 16 + l;
    a1[row] = s1; e1[row] = __expf(s1); f1[row] = __expf(0.2f * s1);
    a2[row] = s2; e2[row] = __expf(s2); f2[row] = __expf(0.2f * s2);
  }
  int jw = j0 + w * 16 + (l >> 4) * 4;
  #pragma unroll
  for (int dt = 0; dt < 16; ++dt) {
    int d = dt * 16 + (l & 15);
    bf16x4 o = { (bf16)acc[dt][0], (bf16)acc[dt][1], (bf16)acc[dt][2], (bf16)acc[dt][3] };
    *(bf16x4*)(hT + ((size_t)(b * D_ + d)) * N_ + jw) = o;   // hT[b][d][j]
  }
}

// ---- kernel 2: column partial sums + adj->bitmask (vectorized, ballot-free) ----
// thread t owns 8 consecutive columns j = t*8..t*8+7; reads int4 x2 per row
// (32 B/lane, 8 KB/wave/row), packs the 8-bit mask locally, byte store.
__global__ __launch_bounds__(256) void k_colstats(
    const int* __restrict__ adj,
    const float* __restrict__ a1, const float* __restrict__ e1, const float* __restrict__ f1,
    const float* __restrict__ a2,
    float* __restrict__ partA, float* __restrict__ partB,
    unsigned char* __restrict__ maskB) {
  int blk = blockIdx.x;              // 512 blocks: b*NSEG + is
  int b  = blk >> 6;
  int is = blk & (NSEG - 1);
  int t = threadIdx.x;
  int ibase = is * SROWS;
  __shared__ float a1s[SROWS], e1s[SROWS], f1s[SROWS];
  if (t < SROWS) {
    int gi = b * N_ + ibase + t;
    a1s[t] = a1[gi]; e1s[t] = e1[gi]; f1s[t] = f1[gi];
  }
  __syncthreads();
  int j0 = t * 8;
  float4 a2lo = *(const float4*)(a2 + b * N_ + j0);
  float4 a2hi = *(const float4*)(a2 + b * N_ + j0 + 4);
  float a2v[8] = {a2lo.x, a2lo.y, a2lo.z, a2lo.w, a2hi.x, a2hi.y, a2hi.z, a2hi.w};
  float SA[8], SB[8];
  #pragma unroll
  for (int e = 0; e < 8; ++e) { SA[e] = 0.f; SB[e] = 0.f; }
  const int* arow = adj + ((size_t)(b * N_ + ibase)) * N_ + j0;
  unsigned char* mrow = maskB + (size_t)(b * N_ + ibase) * (N_ / 8) + t;
  #pragma unroll 4
  for (int ii = 0; ii < SROWS; ++ii) {
    int4 v0 = *(const int4*)(arow + (size_t)ii * N_);
    int4 v1 = *(const int4*)(arow + (size_t)ii * N_ + 4);
    float a1i = a1s[ii], e1i = e1s[ii], f1i = f1s[ii];
    int vals[8] = {v0.x, v0.y, v0.z, v0.w, v1.x, v1.y, v1.z, v1.w};
    unsigned int mb = 0;
    #pragma unroll
    for (int e = 0; e < 8; ++e) {
      bool pred = vals[e] != 0;
      mb |= pred ? (1u << e) : 0u;
      float tt = a1i + a2v[e];
      bool gt = tt > 0.f;
      SA[e] += (pred && gt)  ? e1i : 0.f;
      SB[e] += (pred && !gt) ? f1i : 0.f;
    }
    mrow[(size_t)ii * (N_ / 8)] = (unsigned char)mb;
  }
  float* pA = partA + ((size_t)(b * NSEG + is)) * N_ + j0;
  float* pB = partB + ((size_t)(b * NSEG + is)) * N_ + j0;
  *(float4*)(pA)     = float4{SA[0], SA[1], SA[2], SA[3]};
  *(float4*)(pA + 4) = float4{SA[4], SA[5], SA[6], SA[7]};
  *(float4*)(pB)     = float4{SB[0], SB[1], SB[2], SB[3]};
  *(float4*)(pB + 4) = float4{SB[4], SB[5], SB[6], SB[7]};
}

// ---- kernel 3: finish column stats -> E2/s, F2/s ----
__global__ __launch_bounds__(256) void k_colfin(
    const float* __restrict__ partA, const float* __restrict__ partB,
    const float* __restrict__ e2, const float* __restrict__ f2,
    float* __restrict__ e2rs, float* __restrict__ f2rs) {
  int g = blockIdx.x * 256 + threadIdx.x;   // 16384
  int b = g >> 11, j = g & (N_ - 1);
  float SA = 0.f, SB = 0.f;
  #pragma unroll 8
  for (int is = 0; is < NSEG; ++is) {
    SA += partA[((size_t)(b * NSEG + is)) * N_ + j];
    SB += partB[((size_t)(b * NSEG + is)) * N_ + j];
  }
  float s = e2[g] * SA + f2[g] * SB;
  float rs = s > 0.f ? 1.f / s : 0.f;
  e2rs[g] = e2[g] * rs;
  f2rs[g] = f2[g] * rs;
}

// ---- kernel 4: fused att build (cooperative, LDS) + att@h MFMA + elu ----
// grid 512: b = blk&7 (XCD pin, hT_b L2-resident), i-tile 32.
// att tile [32 i][64 j] bf16 built ONCE per block per K-step into dbuf LDS;
// B-fragments (hT) read directly from L2 (no LDS staging).
__global__ __launch_bounds__(256) void k_attmm(
    const bf16* __restrict__ hT, const unsigned char* __restrict__ maskB,
    const float* __restrict__ a1, const float* __restrict__ e1, const float* __restrict__ f1,
    const float* __restrict__ a2, const float* __restrict__ e2rs, const float* __restrict__ f2rs,
    bf16* __restrict__ hid) {
  __shared__ char satt[2][32 * 128];   // 8 KB: row i (128 B), 16B chunks XOR-swizzled
  int blk = blockIdx.x;                // 512 blocks
  int b  = blk & 7;
  int i0 = (blk >> 3) * 32;
  int t = threadIdx.x, w = t >> 6, l = t & 63;
  int l15 = l & 15, lg = l >> 4;
  int ib = t >> 3, jq = t & 7;
  int gi = b * N_ + i0 + ib;
  float a1i = a1[gi], e1i = e1[gi], f1i = f1[gi];
  const unsigned char* mrow = maskB + (size_t)gi * (N_ / 8);
  const float* a2b = a2 + b * N_;
  const float* eb  = e2rs + b * N_;
  const float* fb  = f2rs + b * N_;
  const bf16* hTb = hT + (size_t)b * D_ * N_;
  f32x4 acc[2][4];
  #pragma unroll
  for (int is = 0; is < 2; ++is)
    #pragma unroll
    for (int ds = 0; ds < 4; ++ds) acc[is][ds] = f32x4{0.f, 0.f, 0.f, 0.f};

  #pragma unroll 2
  for (int kb = 0; kb < N_; kb += 64) {
    char* sb = satt[(kb >> 6) & 1];
    int jbase = kb + jq * 8;
    float4 p0 = *(const float4*)(a2b + jbase);
    float4 p1 = *(const float4*)(a2b + jbase + 4);
    float4 q0 = *(const float4*)(eb + jbase);
    float4 q1 = *(const float4*)(eb + jbase + 4);
    float4 r0 = *(const float4*)(fb + jbase);
    float4 r1 = *(const float4*)(fb + jbase + 4);
    unsigned int mb = mrow[(kb >> 3) + jq];
    float a2v[8] = {p0.x,p0.y,p0.z,p0.w,p1.x,p1.y,p1.z,p1.w};
    float ev[8]  = {q0.x,q0.y,q0.z,q0.w,q1.x,q1.y,q1.z,q1.w};
    float fv[8]  = {r0.x,r0.y,r0.z,r0.w,r1.x,r1.y,r1.z,r1.w};
    bf16x8 av;
    #pragma unroll
    for (int e = 0; e < 8; ++e) {
      float tt = a1i + a2v[e];
      bool sel = tt > 0.f;
      float vv = (sel ? e1i : f1i) * (sel ? ev[e] : fv[e]);
      float vm = ((mb >> e) & 1u) ? vv : 0.f;
      av[e] = (bf16)vm;
    }
    bf16x8 bfr[2][4];
    #pragma unroll
    for (int kh = 0; kh < 2; ++kh)
      #pragma unroll
      for (int ds = 0; ds < 4; ++ds)
        bfr[kh][ds] = *(const bf16x8*)(
            hTb + (size_t)(w * 64 + ds * 16 + l15) * N_ + kb + kh * 32 + lg * 8);
    *(bf16x8*)(sb + ib * 128 + ((jq ^ (ib & 7)) * 16)) = av;
    __syncthreads();
    #pragma unroll
    for (int kh = 0; kh < 2; ++kh) {
      int kq = kh * 4 + lg;
      bf16x8 afr[2];
      #pragma unroll
      for (int is = 0; is < 2; ++is) {
        int ra = is * 16 + l15;
        afr[is] = *(const bf16x8*)(sb + ra * 128 + ((kq ^ (ra & 7)) * 16));
      }
      #pragma unroll
      for (int is = 0; is < 2; ++is)
        #pragma unroll
        for (int ds = 0; ds < 4; ++ds)
          acc[is][ds] = __builtin_amdgcn_mfma_f32_16x16x32_bf16(
              afr[is], bfr[kh][ds], acc[is][ds], 0, 0, 0);
    }
  }
  #pragma unroll
  for (int is = 0; is < 2; ++is) {
    int ibr = i0 + is * 16 + lg * 4;
    #pragma unroll
    for (int ds = 0; ds < 4; ++ds) {
      int d = w * 64 + ds * 16 + l15;
      #pragma unroll
      for (int r = 0; r < 4; ++r) {
        float vv = acc[is][ds][r];
        float hv = vv > 0.f ? vv : __expf(vv) - 1.f;
        hid[((size_t)(b * N_ + ibr + r)) * D_ + d] = (bf16)hv;
      }
    }
  }
}

// ---- kernel 5: out = hid @ han_w + han_b (f32 out) ----
__global__ __launch_bounds__(256) void k_gemm_out(
    const bf16* __restrict__ hid, const bf16* __restrict__ hwt,
    const float* __restrict__ hb, float* __restrict__ out) {
  int blk = blockIdx.x;            // 256 blocks
  int b = blk >> 5;
  int i0 = (blk & 31) * 64;
  int w = threadIdx.x >> 6, l = threadIdx.x & 63;
  int ir = i0 + w * 16 + (l & 15);
  const bf16* hrow = hid + ((size_t)(b * N_ + ir)) * D_;
  int koff = 8 * (l >> 4);
  f32x4 acc[16];
  #pragma unroll
  for (int i = 0; i < 16; ++i) acc[i] = f32x4{0.f, 0.f, 0.f, 0.f};
  for (int kb = 0; kb < D_; kb += 32) {
    bf16x8 af = *(const bf16x8*)(hrow + kb + koff);
    #pragma unroll
    for (int dt = 0; dt < 16; ++dt) {
      bf16x8 bfr = *(const bf16x8*)(hwt + (dt * 16 + (l & 15)) * D_ + kb + koff);
      acc[dt] = __builtin_amdgcn_mfma_f32_16x16x32_bf16(af, bfr, acc[dt], 0, 0, 0);
    }
  }
  int iw = i0 + w * 16 + (l >> 4) * 4;
  #pragma unroll
  for (int dt = 0; dt < 16; ++dt) {
    int d = dt * 16 + (l & 15);
    float bias = hb[d];
    #pragma unroll
    for (int r = 0; r < 4; ++r)
      out[((size_t)(b * N_ + iw + r)) * D_ + d] = acc[dt][r] + bias;
  }
}

extern "C" void kernel_launch(void* const* d_in, const int* in_sizes, int n_in,
                              void* d_out, int out_size, void* d_ws, size_t ws_size,
                              hipStream_t stream) {
  (void)in_sizes; (void)n_in; (void)out_size; (void)ws_size;
  const float* x   = (const float*)d_in[0];
  const int*   adj = (const int*)d_in[1];
  const float* W   = (const float*)d_in[2];
  const float* a   = (const float*)d_in[3];
  const float* hw  = (const float*)d_in[4];
  const float* hb  = (const float*)d_in[5];
  float* out = (float*)d_out;

  char* ws = (char*)d_ws;
  size_t off = 0;
  auto alloc = [&](size_t bytes) -> char* {
    char* p = ws + off;
    off += (bytes + 255) & ~(size_t)255;
    return p;
  };
  float* a1   = (float*)alloc(BN * 4);
  float* e1   = (float*)alloc(BN * 4);
  float* f1   = (float*)alloc(BN * 4);
  float* a2   = (float*)alloc(BN * 4);
  float* e2   = (float*)alloc(BN * 4);
  float* f2   = (float*)alloc(BN * 4);
  float* e2rs = (float*)alloc(BN * 4);
  float* f2rs = (float*)alloc(BN * 4);
  float* partA = (float*)alloc((size_t)B_ * NSEG * N_ * 4);   // 4 MB
  float* partB = (float*)alloc((size_t)B_ * NSEG * N_ * 4);   // 4 MB
  unsigned char* maskB = (unsigned char*)alloc((size_t)BN * (N_ / 8)); // 4 MB
  bf16* hT  = (bf16*)alloc((size_t)B_ * D_ * N_ * 2);   // 8 MB
  bf16* hid = (bf16*)alloc((size_t)BN * D_ * 2);        // 8 MB
  bf16* wt  = (bf16*)alloc((size_t)D_ * D_ * 2);
  bf16* hwt = (bf16*)alloc((size_t)D_ * D_ * 2);

  k_transpose_w<<<256, 256, 0, stream>>>(W, hw, wt, hwt);
  k_gemm_h<<<256, 256, 0, stream>>>(x, wt, a, hT, a1, e1, f1, a2, e2, f2);
  k_colstats<<<B_ * NSEG, 256, 0, stream>>>(adj, a1, e1, f1, a2, partA, partB, maskB);
  k_colfin<<<BN / 256, 256, 0, stream>>>(partA, partB, e2, f2, e2rs, f2rs);
  k_attmm<<<512, 256, 0, stream>>>(hT, maskB, a1, e1, f1, a2, e2rs, f2rs, hid);
  k_gemm_out<<<256, 256, 0, stream>>>(hid, hwt, hb, out);
}

// Round 4
// 131.448 us; speedup vs baseline: 1.6945x; 1.1905x over previous
//
#include <hip/hip_runtime.h>
#include <hip/hip_bf16.h>
#include <stdint.h>

#define B_ 8
#define N_ 2048
#define D_ 256
#define BN (B_*N_)
#define NSEG 64
#define SROWS (N_/NSEG)   // 32 rows per segment

typedef __bf16 bf16;
typedef bf16 bf16x8 __attribute__((ext_vector_type(8)));
typedef bf16 bf16x4 __attribute__((ext_vector_type(4)));
typedef float f32x4 __attribute__((ext_vector_type(4)));

// ---- kernel 0: transpose weights to bf16 [d][k] ----
__global__ __launch_bounds__(256) void k_transpose_w(
    const float* __restrict__ w, const float* __restrict__ hw,
    bf16* __restrict__ wt, bf16* __restrict__ hwt) {
  int t = blockIdx.x * 256 + threadIdx.x;   // 65536 total
  int d = t >> 8, k = t & 255;
  wt[t]  = (bf16)w[k * D_ + d];
  hwt[t] = (bf16)hw[k * D_ + d];
}

// ---- kernel 1: h^T = (x@W)^T in bf16 (MFMA), fused with a1/a2 row stats ----
__global__ __launch_bounds__(256) void k_gemm_h(
    const float* __restrict__ x, const bf16* __restrict__ wt,
    const float* __restrict__ avec, bf16* __restrict__ hT,
    float* __restrict__ a1, float* __restrict__ e1, float* __restrict__ f1,
    float* __restrict__ a2, float* __restrict__ e2, float* __restrict__ f2) {
  int blk = blockIdx.x;            // 256 blocks
  int b = blk >> 5;
  int j0 = (blk & 31) * 64;
  int w = threadIdx.x >> 6, l = threadIdx.x & 63;
  int jr = j0 + w * 16 + (l & 15);
  const float* xrow = x + ((size_t)(b * N_ + jr)) * D_;
  int koff = 8 * (l >> 4);
  f32x4 acc[16];
  #pragma unroll
  for (int i = 0; i < 16; ++i) acc[i] = f32x4{0.f, 0.f, 0.f, 0.f};
  float s1 = 0.f, s2 = 0.f;
  for (int kb = 0; kb < D_; kb += 32) {
    float4 xa = *(const float4*)(xrow + kb + koff);
    float4 xb = *(const float4*)(xrow + kb + koff + 4);
    float4 ua = *(const float4*)(avec + kb + koff);
    float4 ub = *(const float4*)(avec + kb + koff + 4);
    float4 va = *(const float4*)(avec + D_ + kb + koff);
    float4 vb = *(const float4*)(avec + D_ + kb + koff + 4);
    s1 = fmaf(xa.x, ua.x, fmaf(xa.y, ua.y, fmaf(xa.z, ua.z, fmaf(xa.w, ua.w, s1))));
    s1 = fmaf(xb.x, ub.x, fmaf(xb.y, ub.y, fmaf(xb.z, ub.z, fmaf(xb.w, ub.w, s1))));
    s2 = fmaf(xa.x, va.x, fmaf(xa.y, va.y, fmaf(xa.z, va.z, fmaf(xa.w, va.w, s2))));
    s2 = fmaf(xb.x, vb.x, fmaf(xb.y, vb.y, fmaf(xb.z, vb.z, fmaf(xb.w, vb.w, s2))));
    bf16x8 af = { (bf16)xa.x, (bf16)xa.y, (bf16)xa.z, (bf16)xa.w,
                  (bf16)xb.x, (bf16)xb.y, (bf16)xb.z, (bf16)xb.w };
    #pragma unroll
    for (int dt = 0; dt < 16; ++dt) {
      bf16x8 bfr = *(const bf16x8*)(wt + (dt * 16 + (l & 15)) * D_ + kb + koff);
      acc[dt] = __builtin_amdgcn_mfma_f32_16x16x32_bf16(af, bfr, acc[dt], 0, 0, 0);
    }
  }
  // row-stat reduction: lanes l, l^16, l^32, l^48 share row jr
  s1 += __shfl_xor(s1, 16); s1 += __shfl_xor(s1, 32);
  s2 += __shfl_xor(s2, 16); s2 += __shfl_xor(s2, 32);
  if (l < 16) {
    int row = b * N_ + j0 + w * 16 + l;
    a1[row] = s1; e1[row] = __expf(s1); f1[row] = __expf(0.2f * s1);
    a2[row] = s2; e2[row] = __expf(s2); f2[row] = __expf(0.2f * s2);
  }
  int jw = j0 + w * 16 + (l >> 4) * 4;
  #pragma unroll
  for (int dt = 0; dt < 16; ++dt) {
    int d = dt * 16 + (l & 15);
    bf16x4 o = { (bf16)acc[dt][0], (bf16)acc[dt][1], (bf16)acc[dt][2], (bf16)acc[dt][3] };
    *(bf16x4*)(hT + ((size_t)(b * D_ + d)) * N_ + jw) = o;   // hT[b][d][j]
  }
}

// ---- kernel 2: column partial sums + adj->bitmask (vectorized, ballot-free) ----
__global__ __launch_bounds__(256) void k_colstats(
    const int* __restrict__ adj,
    const float* __restrict__ a1, const float* __restrict__ e1, const float* __restrict__ f1,
    const float* __restrict__ a2,
    float* __restrict__ partA, float* __restrict__ partB,
    unsigned char* __restrict__ maskB) {
  int blk = blockIdx.x;              // 512 blocks: b*NSEG + is
  int b  = blk >> 6;
  int is = blk & (NSEG - 1);
  int t = threadIdx.x;
  int ibase = is * SROWS;
  __shared__ float a1s[SROWS], e1s[SROWS], f1s[SROWS];
  if (t < SROWS) {
    int gi = b * N_ + ibase + t;
    a1s[t] = a1[gi]; e1s[t] = e1[gi]; f1s[t] = f1[gi];
  }
  __syncthreads();
  int j0 = t * 8;
  float4 a2lo = *(const float4*)(a2 + b * N_ + j0);
  float4 a2hi = *(const float4*)(a2 + b * N_ + j0 + 4);
  float a2v[8] = {a2lo.x, a2lo.y, a2lo.z, a2lo.w, a2hi.x, a2hi.y, a2hi.z, a2hi.w};
  float SA[8], SB[8];
  #pragma unroll
  for (int e = 0; e < 8; ++e) { SA[e] = 0.f; SB[e] = 0.f; }
  const int* arow = adj + ((size_t)(b * N_ + ibase)) * N_ + j0;
  unsigned char* mrow = maskB + (size_t)(b * N_ + ibase) * (N_ / 8) + t;
  #pragma unroll 4
  for (int ii = 0; ii < SROWS; ++ii) {
    int4 v0 = *(const int4*)(arow + (size_t)ii * N_);
    int4 v1 = *(const int4*)(arow + (size_t)ii * N_ + 4);
    float a1i = a1s[ii], e1i = e1s[ii], f1i = f1s[ii];
    int vals[8] = {v0.x, v0.y, v0.z, v0.w, v1.x, v1.y, v1.z, v1.w};
    unsigned int mb = 0;
    #pragma unroll
    for (int e = 0; e < 8; ++e) {
      bool pred = vals[e] != 0;
      mb |= pred ? (1u << e) : 0u;
      float tt = a1i + a2v[e];
      bool gt = tt > 0.f;
      SA[e] += (pred && gt)  ? e1i : 0.f;
      SB[e] += (pred && !gt) ? f1i : 0.f;
    }
    mrow[(size_t)ii * (N_ / 8)] = (unsigned char)mb;
  }
  float* pA = partA + ((size_t)(b * NSEG + is)) * N_ + j0;
  float* pB = partB + ((size_t)(b * NSEG + is)) * N_ + j0;
  *(float4*)(pA)     = float4{SA[0], SA[1], SA[2], SA[3]};
  *(float4*)(pA + 4) = float4{SA[4], SA[5], SA[6], SA[7]};
  *(float4*)(pB)     = float4{SB[0], SB[1], SB[2], SB[3]};
  *(float4*)(pB + 4) = float4{SB[4], SB[5], SB[6], SB[7]};
}

// ---- kernel 3: finish column stats -> E2/s, F2/s ----
__global__ __launch_bounds__(256) void k_colfin(
    const float* __restrict__ partA, const float* __restrict__ partB,
    const float* __restrict__ e2, const float* __restrict__ f2,
    float* __restrict__ e2rs, float* __restrict__ f2rs) {
  int g = blockIdx.x * 256 + threadIdx.x;   // 16384
  int b = g >> 11, j = g & (N_ - 1);
  float SA = 0.f, SB = 0.f;
  #pragma unroll 8
  for (int is = 0; is < NSEG; ++is) {
    SA += partA[((size_t)(b * NSEG + is)) * N_ + j];
    SB += partB[((size_t)(b * NSEG + is)) * N_ + j];
  }
  float s = e2[g] * SA + f2[g] * SB;
  float rs = s > 0.f ? 1.f / s : 0.f;
  e2rs[g] = e2[g] * rs;
  f2rs[g] = f2[g] * rs;
}

// ---- kernel 4: fused att build + att@h + elu + (hid @ han_w + b) ----
// grid 512: b = blk&7 (XCD pin), i-tile 32. Per K-step: att tile built once
// cooperatively into dbuf LDS from LDS-preloaded sources (zero global loads on
// the build path); B-frags register-prefetched one iter ahead; RAW s_barrier
// with lgkmcnt-only fence so prefetch loads stay in flight across the barrier.
// Epilogue: elu -> swizzled LDS hid tile -> second MFMA phase vs hwt -> out.
__global__ __launch_bounds__(256) void k_attmm(
    const bf16* __restrict__ hT, const unsigned char* __restrict__ maskB,
    const float* __restrict__ a1, const float* __restrict__ e1, const float* __restrict__ f1,
    const float* __restrict__ a2, const float* __restrict__ e2rs, const float* __restrict__ f2rs,
    const bf16* __restrict__ hwt, const float* __restrict__ hb,
    float* __restrict__ out) {
  __shared__ float s_src[3 * N_];            // a2 | e2rs | f2rs  (24 KB)
  __shared__ unsigned char s_mask[32 * 256]; // mask rows i0..i0+31 (8 KB)
  __shared__ char s_att[2][32 * 128];        // att dbuf, XOR-swizzled (8 KB)
  __shared__ char s_hid[32 * 512];           // hid tile, XOR-swizzled (16 KB)

  int blk = blockIdx.x;                // 512 blocks
  int b  = blk & 7;
  int i0 = (blk >> 3) * 32;
  int t = threadIdx.x, w = t >> 6, l = t & 63;
  int l15 = l & 15, lg = l >> 4;
  int ib = t >> 3, jq = t & 7;

  // ---- preload att sources + mask slice into LDS ----
  {
    #pragma unroll
    for (int s = 0; s < 6; ++s) {
      int idx = t + s * 256;             // float4 index 0..1535
      int arr = idx >> 9, pos = (idx & 511) * 4;
      const float* src = (arr == 0) ? (a2 + b * N_) : (arr == 1) ? (e2rs + b * N_) : (f2rs + b * N_);
      *(float4*)(s_src + arr * N_ + pos) = *(const float4*)(src + pos);
    }
    int row = t >> 3, seg = t & 7;       // 32 B of mask per thread
    const uint4* g = (const uint4*)(maskB + ((size_t)(b * N_ + i0 + row)) * (N_ / 8) + seg * 32);
    uint4* ds0 = (uint4*)(s_mask + row * 256 + seg * 32);
    ds0[0] = g[0]; ds0[1] = g[1];
  }
  __syncthreads();
  // ---- pack this thread's 32 per-iter mask bytes into 8 regs ----
  unsigned int mreg[8];
  #pragma unroll
  for (int q = 0; q < 8; ++q) {
    unsigned int b0 = s_mask[ib * 256 + (4 * q + 0) * 8 + jq];
    unsigned int b1 = s_mask[ib * 256 + (4 * q + 1) * 8 + jq];
    unsigned int b2 = s_mask[ib * 256 + (4 * q + 2) * 8 + jq];
    unsigned int b3 = s_mask[ib * 256 + (4 * q + 3) * 8 + jq];
    mreg[q] = b0 | (b1 << 8) | (b2 << 16) | (b3 << 24);
  }
  int gi = b * N_ + i0 + ib;
  float a1i = a1[gi], e1i = e1[gi], f1i = f1[gi];
  const bf16* hTb = hT + (size_t)b * D_ * N_;

  f32x4 acc[2][4];
  #pragma unroll
  for (int is = 0; is < 2; ++is)
    #pragma unroll
    for (int ds = 0; ds < 4; ++ds) acc[is][ds] = f32x4{0.f, 0.f, 0.f, 0.f};

  // prologue: B-frags for iter 0
  bf16x8 bfrC[2][4], bfrN[2][4];
  #pragma unroll
  for (int kh = 0; kh < 2; ++kh)
    #pragma unroll
    for (int ds = 0; ds < 4; ++ds)
      bfrC[kh][ds] = *(const bf16x8*)(
          hTb + (size_t)(w * 64 + ds * 16 + l15) * N_ + kh * 32 + lg * 8);

  for (int it = 0; it < 32; ++it) {
    int kb = it * 64;
    int kbn = (it == 31) ? 0 : kb + 64;      // wrap: last prefetch unused
    // ---- prefetch next iter's B-frags (stay in flight across raw barrier) ----
    #pragma unroll
    for (int kh = 0; kh < 2; ++kh)
      #pragma unroll
      for (int ds = 0; ds < 4; ++ds)
        bfrN[kh][ds] = *(const bf16x8*)(
            hTb + (size_t)(w * 64 + ds * 16 + l15) * N_ + kbn + kh * 32 + lg * 8);
    // ---- build 8 att entries from LDS sources ----
    int jb = kb + jq * 8;
    float4 p0 = *(const float4*)(s_src + jb);
    float4 p1 = *(const float4*)(s_src + jb + 4);
    float4 q0 = *(const float4*)(s_src + N_ + jb);
    float4 q1 = *(const float4*)(s_src + N_ + jb + 4);
    float4 r0 = *(const float4*)(s_src + 2 * N_ + jb);
    float4 r1 = *(const float4*)(s_src + 2 * N_ + jb + 4);
    unsigned int mb = (mreg[it >> 2] >> ((it & 3) * 8)) & 255u;
    float a2v[8] = {p0.x,p0.y,p0.z,p0.w,p1.x,p1.y,p1.z,p1.w};
    float ev[8]  = {q0.x,q0.y,q0.z,q0.w,q1.x,q1.y,q1.z,q1.w};
    float fv[8]  = {r0.x,r0.y,r0.z,r0.w,r1.x,r1.y,r1.z,r1.w};
    bf16x8 av;
    #pragma unroll
    for (int e = 0; e < 8; ++e) {
      float tt = a1i + a2v[e];
      bool sel = tt > 0.f;
      float vv = (sel ? e1i : f1i) * (sel ? ev[e] : fv[e]);
      float vm = ((mb >> e) & 1u) ? vv : 0.f;
      av[e] = (bf16)vm;
    }
    char* sb = s_att[it & 1];
    *(bf16x8*)(sb + ib * 128 + ((jq ^ (ib & 7)) * 16)) = av;
    // raw barrier: drain LDS ops only; vmem prefetch stays outstanding
    asm volatile("s_waitcnt lgkmcnt(0)" ::: "memory");
    __builtin_amdgcn_sched_barrier(0);
    __builtin_amdgcn_s_barrier();
    __builtin_amdgcn_sched_barrier(0);
    // ---- MFMA: A from LDS att tile, B prefetched regs ----
    #pragma unroll
    for (int kh = 0; kh < 2; ++kh) {
      int kq = kh * 4 + lg;
      bf16x8 afr[2];
      #pragma unroll
      for (int is = 0; is < 2; ++is) {
        int ra = is * 16 + l15;
        afr[is] = *(const bf16x8*)(sb + ra * 128 + ((kq ^ (ra & 7)) * 16));
      }
      #pragma unroll
      for (int is = 0; is < 2; ++is)
        #pragma unroll
        for (int ds = 0; ds < 4; ++ds)
          acc[is][ds] = __builtin_amdgcn_mfma_f32_16x16x32_bf16(
              afr[is], bfrC[kh][ds], acc[is][ds], 0, 0, 0);
    }
    #pragma unroll
    for (int kh = 0; kh < 2; ++kh)
      #pragma unroll
      for (int ds = 0; ds < 4; ++ds) bfrC[kh][ds] = bfrN[kh][ds];
  }

  // ---- elu -> bf16 hid tile into swizzled LDS ----
  #pragma unroll
  for (int is = 0; is < 2; ++is) {
    #pragma unroll
    for (int ds = 0; ds < 4; ++ds) {
      int d = w * 64 + ds * 16 + l15;
      int c = d >> 3;
      #pragma unroll
      for (int r = 0; r < 4; ++r) {
        int i = is * 16 + lg * 4 + r;
        float vv = acc[is][ds][r];
        float hv = vv > 0.f ? vv : __expf(vv) - 1.f;
        *(bf16*)(s_hid + i * 512 + ((c ^ (i & 7)) * 16) + (d & 7) * 2) = (bf16)hv;
      }
    }
  }
  __syncthreads();

  // ---- out = hid @ han_w + han_b ----
  f32x4 acc2[2][4];
  #pragma unroll
  for (int is = 0; is < 2; ++is)
    #pragma unroll
    for (int ds = 0; ds < 4; ++ds) acc2[is][ds] = f32x4{0.f, 0.f, 0.f, 0.f};
  #pragma unroll
  for (int kh = 0; kh < 8; ++kh) {
    int kc = kh * 4 + lg;                 // 16B chunk index along k
    bf16x8 afr[2];
    #pragma unroll
    for (int is = 0; is < 2; ++is) {
      int ra = is * 16 + l15;
      afr[is] = *(const bf16x8*)(s_hid + ra * 512 + ((kc ^ (ra & 7)) * 16));
    }
    #pragma unroll
    for (int ds = 0; ds < 4; ++ds) {
      bf16x8 bfr = *(const bf16x8*)(
          hwt + (size_t)(w * 64 + ds * 16 + l15) * D_ + kh * 32 + lg * 8);
      #pragma unroll
      for (int is = 0; is < 2; ++is)
        acc2[is][ds] = __builtin_amdgcn_mfma_f32_16x16x32_bf16(
            afr[is], bfr, acc2[is][ds], 0, 0, 0);
    }
  }
  #pragma unroll
  for (int is = 0; is < 2; ++is) {
    int ibr = i0 + is * 16 + lg * 4;
    #pragma unroll
    for (int ds = 0; ds < 4; ++ds) {
      int d = w * 64 + ds * 16 + l15;
      float bias = hb[d];
      #pragma unroll
      for (int r = 0; r < 4; ++r)
        out[((size_t)(b * N_ + ibr + r)) * D_ + d] = acc2[is][ds][r] + bias;
    }
  }
}

extern "C" void kernel_launch(void* const* d_in, const int* in_sizes, int n_in,
                              void* d_out, int out_size, void* d_ws, size_t ws_size,
                              hipStream_t stream) {
  (void)in_sizes; (void)n_in; (void)out_size; (void)ws_size;
  const float* x   = (const float*)d_in[0];
  const int*   adj = (const int*)d_in[1];
  const float* W   = (const float*)d_in[2];
  const float* a   = (const float*)d_in[3];
  const float* hw  = (const float*)d_in[4];
  const float* hb  = (const float*)d_in[5];
  float* out = (float*)d_out;

  char* ws = (char*)d_ws;
  size_t off = 0;
  auto alloc = [&](size_t bytes) -> char* {
    char* p = ws + off;
    off += (bytes + 255) & ~(size_t)255;
    return p;
  };
  float* a1   = (float*)alloc(BN * 4);
  float* e1   = (float*)alloc(BN * 4);
  float* f1   = (float*)alloc(BN * 4);
  float* a2   = (float*)alloc(BN * 4);
  float* e2   = (float*)alloc(BN * 4);
  float* f2   = (float*)alloc(BN * 4);
  float* e2rs = (float*)alloc(BN * 4);
  float* f2rs = (float*)alloc(BN * 4);
  float* partA = (float*)alloc((size_t)B_ * NSEG * N_ * 4);   // 4 MB
  float* partB = (float*)alloc((size_t)B_ * NSEG * N_ * 4);   // 4 MB
  unsigned char* maskB = (unsigned char*)alloc((size_t)BN * (N_ / 8)); // 4 MB
  bf16* hT  = (bf16*)alloc((size_t)B_ * D_ * N_ * 2);   // 8 MB
  bf16* wt  = (bf16*)alloc((size_t)D_ * D_ * 2);
  bf16* hwt = (bf16*)alloc((size_t)D_ * D_ * 2);

  k_transpose_w<<<256, 256, 0, stream>>>(W, hw, wt, hwt);
  k_gemm_h<<<256, 256, 0, stream>>>(x, wt, a, hT, a1, e1, f1, a2, e2, f2);
  k_colstats<<<B_ * NSEG, 256, 0, stream>>>(adj, a1, e1, f1, a2, partA, partB, maskB);
  k_colfin<<<BN / 256, 256, 0, stream>>>(partA, partB, e2, f2, e2rs, f2rs);
  k_attmm<<<512, 256, 0, stream>>>(hT, maskB, a1, e1, f1, a2, e2rs, f2rs,
                                   hwt, hb, out);
}